// Round 2
// baseline (215.383 us; speedup 1.0000x reference)
//
#include <hip/hip_runtime.h>
#include <hip/hip_bf16.h>

typedef __bf16 bf16x8 __attribute__((ext_vector_type(8)));
typedef __bf16 bf16x4 __attribute__((ext_vector_type(4)));
typedef __bf16 bf16x2 __attribute__((ext_vector_type(2)));
typedef float fx4 __attribute__((ext_vector_type(4)));
typedef float fx16 __attribute__((ext_vector_type(16)));

#define AS1 __attribute__((address_space(1)))
#define AS3 __attribute__((address_space(3)))

// ---------------------------------------------------------------- prep: cast x -> bf16  +  all 4 weight transposes
__global__ __launch_bounds__(256) void prep(const float4* __restrict__ X, __bf16* __restrict__ Xb,
                                            const float* __restrict__ wq, const float* __restrict__ wk,
                                            const float* __restrict__ wv, const float* __restrict__ wo,
                                            __bf16* __restrict__ WqkvT, __bf16* __restrict__ WoT) {
    const int bx = blockIdx.x;
    if (bx < 4096) {
        const int i = bx * 256 + threadIdx.x;
        const float4 v = X[i];
        bf16x4 o = { (__bf16)v.x, (__bf16)v.y, (__bf16)v.z, (__bf16)v.w };
        *(bf16x4*)(Xb + (size_t)i * 4) = o;
        return;
    }
    constexpr int K = 2048;
    __shared__ float t[64][33];
    const int tt = bx - 4096;
    const float* W; __bf16* Wt; int N, loc;
    if (tt < 2048)      { W = wq; Wt = WqkvT;                       N = 2048; loc = tt; }
    else if (tt < 2560) { W = wk; Wt = WqkvT + (size_t)2048 * 2048; N = 512;  loc = tt - 2048; }
    else if (tt < 3072) { W = wv; Wt = WqkvT + (size_t)2560 * 2048; N = 512;  loc = tt - 2560; }
    else                { W = wo; Wt = WoT;                         N = 2048; loc = tt - 3072; }
    const int k0 = (loc & 31) * 64, n0 = (loc >> 5) * 32;
    const int tx = threadIdx.x & 31, ty = threadIdx.x >> 5;
#pragma unroll
    for (int i = 0; i < 8; ++i)
        t[ty + i * 8][tx] = W[(size_t)(k0 + ty + i * 8) * N + n0 + tx];
    __syncthreads();
#pragma unroll
    for (int i = 0; i < 4; ++i) {
        const int nn = ty + i * 8;
        bf16x2 o = { (__bf16)t[tx * 2][nn], (__bf16)t[tx * 2 + 1][nn] };
        *(bf16x2*)&Wt[(size_t)(n0 + nn) * K + k0 + tx * 2] = o;
    }
}

// ------------------------------------------------- QKV GEMM, BM=128 BN=64 BK=32, depth-3 counted-vmcnt
// pipeline over 4 LDS buffers (raw s_barrier, vmcnt never drains to 0 in steady loop),
// XOR-swizzled LDS (pre-swizzled global source + swizzled read col), fused RoPE/split epilogue.
__global__ __launch_bounds__(256) void gemm_qkv(const __bf16* __restrict__ A, const __bf16* __restrict__ Bt,
                                                __bf16* __restrict__ Qr, __bf16* __restrict__ Kr,
                                                __bf16* __restrict__ Vt) {
    constexpr int K = 2048;
    constexpr int BUF = 192 * 32;                        // A 128x32 + B 64x32 (elements)
    __shared__ __align__(16) __bf16 sm[4][BUF];          // 48 KB
    const int tid = threadIdx.x;
    const int wave = tid >> 6, lane = tid & 63;
    const int quad = lane >> 4, l16 = lane & 15;
    const int m0 = blockIdx.x * 128, n0 = blockIdx.y * 64;
    fx4 acc[2][4] = {};

    // 12 staging units of 16rows x 32k x 2B = 1024B = one wave-wide 16B/lane load.
    const int r4 = lane >> 2;
    const int c8s = ((lane & 3) ^ ((r4 >> 1) & 3)) * 8;  // pre-swizzled source col
    const __bf16* csrc[3]; int cdst[3];
#pragma unroll
    for (int it = 0; it < 3; ++it) {
        const int idx = wave * 3 + it;
        if (idx < 8) {
            csrc[it] = A + (size_t)(m0 + idx * 16 + r4) * K + c8s;
            cdst[it] = idx * 512 + lane * 8;
        } else {
            const int s = idx - 8;
            csrc[it] = Bt + (size_t)(n0 + s * 16 + r4) * K + c8s;
            cdst[it] = 4096 + s * 512 + lane * 8;
        }
    }
    const int colr = (quad ^ ((l16 >> 1) & 3)) * 8;      // swizzled read col
    const int arow = (wave * 32 + l16) * 32 + colr;      // + i*512
    const int brow = 4096 + l16 * 32 + colr;             // + j*512

    auto compute = [&](const __bf16* cb) {
        bf16x8 af[2], bfr[4];
#pragma unroll
        for (int i = 0; i < 2; ++i) af[i] = *(const bf16x8*)&cb[arow + i * 512];
#pragma unroll
        for (int j = 0; j < 4; ++j) bfr[j] = *(const bf16x8*)&cb[brow + j * 512];
#pragma unroll
        for (int i = 0; i < 2; ++i)
#pragma unroll
            for (int j = 0; j < 4; ++j)
                acc[i][j] = __builtin_amdgcn_mfma_f32_16x16x32_bf16(af[i], bfr[j], acc[i][j], 0, 0, 0);
    };

    // prologue: issue tiles 0,1,2
#pragma unroll
    for (int pt = 0; pt < 3; ++pt)
#pragma unroll
        for (int it = 0; it < 3; ++it)
            __builtin_amdgcn_global_load_lds((const AS1 void*)(csrc[it] + pt * 32),
                                             (AS3 void*)&sm[pt][cdst[it]], 16, 0, 0);

#pragma unroll 1
    for (int t = 0; t < 61; ++t) {
        asm volatile("s_waitcnt vmcnt(6) lgkmcnt(0)" ::: "memory");  // tile t landed; 2 tiles in flight
        __builtin_amdgcn_s_barrier();
        const int kofs = (t + 3) * 32;
#pragma unroll
        for (int it = 0; it < 3; ++it)
            __builtin_amdgcn_global_load_lds((const AS1 void*)(csrc[it] + kofs),
                                             (AS3 void*)&sm[(t + 3) & 3][cdst[it]], 16, 0, 0);
        compute(sm[t & 3]);
    }
    asm volatile("s_waitcnt vmcnt(6) lgkmcnt(0)" ::: "memory"); __builtin_amdgcn_s_barrier(); compute(sm[1]);
    asm volatile("s_waitcnt vmcnt(3) lgkmcnt(0)" ::: "memory"); __builtin_amdgcn_s_barrier(); compute(sm[2]);
    asm volatile("s_waitcnt vmcnt(0) lgkmcnt(0)" ::: "memory"); __builtin_amdgcn_s_barrier(); compute(sm[3]);

    const int by = blockIdx.y;
    if (by < 40) {
        const float scale = (by < 32) ? 0.18033688011112042f : 1.0f;   // Q: 0.125*log2(e)
        __bf16* base = (by < 32) ? (Qr + (size_t)by * 2048 * 64)
                                 : (Kr + (size_t)(by - 32) * 2048 * 64);
#pragma unroll
        for (int jj = 0; jj < 2; ++jj) {
            const int dlo = jj * 16 + l16;
            const float inv = __builtin_amdgcn_exp2f(-(float)dlo * 0.41524101186092029f);
#pragma unroll
            for (int i = 0; i < 2; ++i)
#pragma unroll
                for (int r = 0; r < 4; ++r) {
                    const int s = m0 + wave * 32 + i * 16 + quad * 4 + r;
                    float sn, cs;
                    __sincosf((float)s * inv, &sn, &cs);
                    const float lo = acc[i][jj][r], hv = acc[i][jj + 2][r];
                    base[(size_t)s * 64 + dlo]      = (__bf16)((lo * cs - hv * sn) * scale);
                    base[(size_t)s * 64 + dlo + 32] = (__bf16)((hv * cs + lo * sn) * scale);
                }
        }
    } else {
        __bf16* vb = Vt + (size_t)(by - 40) * 64 * 2048;
#pragma unroll
        for (int i = 0; i < 2; ++i)
#pragma unroll
            for (int j = 0; j < 4; ++j) {
                const int d = j * 16 + l16;
                const int s0 = m0 + wave * 32 + i * 16 + quad * 4;
                bf16x4 p;
#pragma unroll
                for (int r = 0; r < 4; ++r) p[r] = (__bf16)acc[i][j][r];
                *(bf16x4*)&vb[(size_t)d * 2048 + s0] = p;
            }
    }
}

// ------------------------------------------------- out-projection GEMM, BM=128 BN=64 BK=32,
// same depth-3 counted-vmcnt pipeline; writes f32 C directly (no split-K, no reduce pass).
__global__ __launch_bounds__(256) void gemm_out(const __bf16* __restrict__ A, const __bf16* __restrict__ Bt,
                                                float* __restrict__ C) {
    constexpr int K = 2048;
    constexpr int BUF = 192 * 32;
    __shared__ __align__(16) __bf16 sm[4][BUF];          // 48 KB
    const int tid = threadIdx.x;
    const int wave = tid >> 6, lane = tid & 63;
    const int quad = lane >> 4, l16 = lane & 15;
    const int m0 = blockIdx.x * 128, n0 = blockIdx.y * 64;
    fx4 acc[2][4] = {};

    const int r4 = lane >> 2;
    const int c8s = ((lane & 3) ^ ((r4 >> 1) & 3)) * 8;
    const __bf16* csrc[3]; int cdst[3];
#pragma unroll
    for (int it = 0; it < 3; ++it) {
        const int idx = wave * 3 + it;
        if (idx < 8) {
            csrc[it] = A + (size_t)(m0 + idx * 16 + r4) * K + c8s;
            cdst[it] = idx * 512 + lane * 8;
        } else {
            const int s = idx - 8;
            csrc[it] = Bt + (size_t)(n0 + s * 16 + r4) * K + c8s;
            cdst[it] = 4096 + s * 512 + lane * 8;
        }
    }
    const int colr = (quad ^ ((l16 >> 1) & 3)) * 8;
    const int arow = (wave * 32 + l16) * 32 + colr;
    const int brow = 4096 + l16 * 32 + colr;

    auto compute = [&](const __bf16* cb) {
        bf16x8 af[2], bfr[4];
#pragma unroll
        for (int i = 0; i < 2; ++i) af[i] = *(const bf16x8*)&cb[arow + i * 512];
#pragma unroll
        for (int j = 0; j < 4; ++j) bfr[j] = *(const bf16x8*)&cb[brow + j * 512];
#pragma unroll
        for (int i = 0; i < 2; ++i)
#pragma unroll
            for (int j = 0; j < 4; ++j)
                acc[i][j] = __builtin_amdgcn_mfma_f32_16x16x32_bf16(af[i], bfr[j], acc[i][j], 0, 0, 0);
    };

#pragma unroll
    for (int pt = 0; pt < 3; ++pt)
#pragma unroll
        for (int it = 0; it < 3; ++it)
            __builtin_amdgcn_global_load_lds((const AS1 void*)(csrc[it] + pt * 32),
                                             (AS3 void*)&sm[pt][cdst[it]], 16, 0, 0);

#pragma unroll 1
    for (int t = 0; t < 61; ++t) {
        asm volatile("s_waitcnt vmcnt(6) lgkmcnt(0)" ::: "memory");
        __builtin_amdgcn_s_barrier();
        const int kofs = (t + 3) * 32;
#pragma unroll
        for (int it = 0; it < 3; ++it)
            __builtin_amdgcn_global_load_lds((const AS1 void*)(csrc[it] + kofs),
                                             (AS3 void*)&sm[(t + 3) & 3][cdst[it]], 16, 0, 0);
        compute(sm[t & 3]);
    }
    asm volatile("s_waitcnt vmcnt(6) lgkmcnt(0)" ::: "memory"); __builtin_amdgcn_s_barrier(); compute(sm[1]);
    asm volatile("s_waitcnt vmcnt(3) lgkmcnt(0)" ::: "memory"); __builtin_amdgcn_s_barrier(); compute(sm[2]);
    asm volatile("s_waitcnt vmcnt(0) lgkmcnt(0)" ::: "memory"); __builtin_amdgcn_s_barrier(); compute(sm[3]);

#pragma unroll
    for (int i = 0; i < 2; ++i)
#pragma unroll
        for (int j = 0; j < 4; ++j) {
            const int row = m0 + wave * 32 + i * 16 + quad * 4;
            const int col = n0 + j * 16 + l16;
#pragma unroll
            for (int r = 0; r < 4; ++r)
                C[(size_t)(row + r) * 2048 + col] = acc[i][j][r];
        }
}

// ------------------------------------------------- flash attention: no-P-LDS + 8-wave split-K + LDS dbuf
// grid (16 q-tiles of 128, 32 heads), 512 thr = 8 waves. Waves 0-3 even key-tiles, 4-7 odd,
// private K/V buffers per group, DOUBLE-BUFFERED: one barrier per iteration.
// PV B-operand packed straight from exp2'd score regs (permuted-V).
// Fixed-max softmax -> cross-group combine via plain adds through LDS (overlaid on smem[0]).
__global__ __launch_bounds__(512, 4) void flash_attn(const __bf16* __restrict__ Qr, const __bf16* __restrict__ Kr,
                                                     const __bf16* __restrict__ Vt, __bf16* __restrict__ O) {
    constexpr int S = 2048;
    __shared__ __align__(16) __bf16 smem[2][4 * 64 * 72];   // 73728 B, 2 buffers
    const int qt = blockIdx.x, h = blockIdx.y, kvh = h >> 2;
    const int tid = threadIdx.x, wave = tid >> 6, lane = tid & 63;
    const int grp = wave >> 2, w4 = wave & 3;
    const int l32 = lane & 31, hi = lane >> 5;
    const int goff = grp * 2 * 4608;                        // group's K/V region inside a buffer

    const int qrow = qt * 128 + w4 * 32 + l32;
    const __bf16* qptr = Qr + ((size_t)h * S + qrow) * 64;
    bf16x8 qf[4];
#pragma unroll
    for (int kc = 0; kc < 4; ++kc) qf[kc] = *(const bf16x8*)(qptr + kc * 16 + hi * 8);

    const __bf16* Kbase = Kr + (size_t)kvh * S * 64;
    const __bf16* Vbase = Vt + (size_t)kvh * 64 * S;

    const int gtid = tid & 255;
    const int krow = gtid >> 3;                 // 0..31
    const int kcol = (gtid & 7) * 8;
    const int vslot = (kcol & 48) | ((kcol & 8) >> 1);   // permuted dest of keys [kcol, kcol+4)

    // prefetch tile 0 of this group (kt = grp)
    bf16x8 kreg0 = *(const bf16x8*)(Kbase + (size_t)(grp * 64 + krow) * 64 + kcol);
    bf16x8 kreg1 = *(const bf16x8*)(Kbase + (size_t)(grp * 64 + 32 + krow) * 64 + kcol);
    bf16x8 vreg0 = *(const bf16x8*)(Vbase + (size_t)krow * S + grp * 64 + kcol);
    bf16x8 vreg1 = *(const bf16x8*)(Vbase + (size_t)(32 + krow) * S + grp * 64 + kcol);

    fx16 ov0, ov1;
#pragma unroll
    for (int i = 0; i < 16; ++i) { ov0[i] = 0.f; ov1[i] = 0.f; }
    float l_acc = 0.f;

    // stage tile 0 into buf 0, then prefetch tile 1 (kt = 2 + grp)
    {
        __bf16* nK = &smem[0][goff];
        __bf16* nV = nK + 4608;
        *(bf16x8*)&nK[krow * 72 + kcol] = kreg0;
        *(bf16x8*)&nK[(32 + krow) * 72 + kcol] = kreg1;
        bf16x4 v0lo = { vreg0[0], vreg0[1], vreg0[2], vreg0[3] };
        bf16x4 v0hi = { vreg0[4], vreg0[5], vreg0[6], vreg0[7] };
        bf16x4 v1lo = { vreg1[0], vreg1[1], vreg1[2], vreg1[3] };
        bf16x4 v1hi = { vreg1[4], vreg1[5], vreg1[6], vreg1[7] };
        *(bf16x4*)&nV[krow * 72 + vslot]            = v0lo;
        *(bf16x4*)&nV[krow * 72 + vslot + 8]        = v0hi;
        *(bf16x4*)&nV[(32 + krow) * 72 + vslot]     = v1lo;
        *(bf16x4*)&nV[(32 + krow) * 72 + vslot + 8] = v1hi;
        const int kt1 = 2 + grp;
        kreg0 = *(const bf16x8*)(Kbase + (size_t)(kt1 * 64 + krow) * 64 + kcol);
        kreg1 = *(const bf16x8*)(Kbase + (size_t)(kt1 * 64 + 32 + krow) * 64 + kcol);
        vreg0 = *(const bf16x8*)(Vbase + (size_t)krow * S + kt1 * 64 + kcol);
        vreg1 = *(const bf16x8*)(Vbase + (size_t)(32 + krow) * S + kt1 * 64 + kcol);
    }
    __syncthreads();

    for (int it = 0; it < 16; ++it) {
        __bf16* lKg = &smem[it & 1][goff];
        __bf16* lVg = lKg + 4608;

        // stage tile it+1 into the other buffer; prefetch tile it+2
        if (it + 1 < 16) {
            __bf16* nK = &smem[(it + 1) & 1][goff];
            __bf16* nV = nK + 4608;
            *(bf16x8*)&nK[krow * 72 + kcol] = kreg0;
            *(bf16x8*)&nK[(32 + krow) * 72 + kcol] = kreg1;
            bf16x4 v0lo = { vreg0[0], vreg0[1], vreg0[2], vreg0[3] };
            bf16x4 v0hi = { vreg0[4], vreg0[5], vreg0[6], vreg0[7] };
            bf16x4 v1lo = { vreg1[0], vreg1[1], vreg1[2], vreg1[3] };
            bf16x4 v1hi = { vreg1[4], vreg1[5], vreg1[6], vreg1[7] };
            *(bf16x4*)&nV[krow * 72 + vslot]            = v0lo;
            *(bf16x4*)&nV[krow * 72 + vslot + 8]        = v0hi;
            *(bf16x4*)&nV[(32 + krow) * 72 + vslot]     = v1lo;
            *(bf16x4*)&nV[(32 + krow) * 72 + vslot + 8] = v1hi;
            const int it2 = (it + 2 < 16) ? it + 2 : 15;   // clamped (redundant reload ok)
            const int ktn = it2 * 2 + grp;
            kreg0 = *(const bf16x8*)(Kbase + (size_t)(ktn * 64 + krow) * 64 + kcol);
            kreg1 = *(const bf16x8*)(Kbase + (size_t)(ktn * 64 + 32 + krow) * 64 + kcol);
            vreg0 = *(const bf16x8*)(Vbase + (size_t)krow * S + ktn * 64 + kcol);
            vreg1 = *(const bf16x8*)(Vbase + (size_t)(32 + krow) * S + ktn * 64 + kcol);
        }

        // S^T = K . Q^T  (k-chunks of 16 d)
        fx16 sc0, sc1;
#pragma unroll
        for (int i = 0; i < 16; ++i) { sc0[i] = 0.f; sc1[i] = 0.f; }
#pragma unroll
        for (int kc = 0; kc < 4; ++kc) {
            const bf16x8 a0 = *(const bf16x8*)&lKg[l32 * 72 + kc * 16 + hi * 8];
            const bf16x8 a1 = *(const bf16x8*)&lKg[(32 + l32) * 72 + kc * 16 + hi * 8];
            sc0 = __builtin_amdgcn_mfma_f32_32x32x16_bf16(a0, qf[kc], sc0, 0, 0, 0);
            sc1 = __builtin_amdgcn_mfma_f32_32x32x16_bf16(a1, qf[kc], sc1, 0, 0, 0);
        }

        // fixed-max softmax (p = exp2(s), Q pre-scaled) fused straight into PV
#pragma unroll
        for (int h2 = 0; h2 < 2; ++h2) {
#pragma unroll
            for (int c = 0; c < 2; ++c) {
                bf16x8 pb;
#pragma unroll
                for (int j = 0; j < 8; ++j) {
                    const float sv = h2 ? sc1[c * 8 + j] : sc0[c * 8 + j];
                    const float p = __builtin_amdgcn_exp2f(sv);
                    l_acc += p;
                    pb[j] = (__bf16)p;
                }
                const int kcv = h2 * 2 + c;
                const bf16x8 va0 = *(const bf16x8*)&lVg[l32 * 72 + kcv * 16 + hi * 8];
                const bf16x8 va1 = *(const bf16x8*)&lVg[(32 + l32) * 72 + kcv * 16 + hi * 8];
                ov0 = __builtin_amdgcn_mfma_f32_32x32x16_bf16(va0, pb, ov0, 0, 0, 0);
                ov1 = __builtin_amdgcn_mfma_f32_32x32x16_bf16(va1, pb, ov1, 0, 0, 0);
            }
        }
        __syncthreads();
    }

    // per-wave l over this group's keys (partner lane^32 holds complement)
    const float l_pair = l_acc + __shfl_xor(l_acc, 32, 64);

    // cross-group combine, overlaid on smem[0]
    fx4* lO = (fx4*)&smem[0][0];                 // [8 chunks][4 w4][64 lanes]
    float* lL = (float*)(&smem[0][0] + 16384);   // byte 32768
    if (grp == 1) {
#pragma unroll
        for (int ic = 0; ic < 4; ++ic) {
            fx4 c0, c1;
#pragma unroll
            for (int r = 0; r < 4; ++r) { c0[r] = ov0[ic * 4 + r]; c1[r] = ov1[ic * 4 + r]; }
            lO[(ic * 4 + w4) * 64 + lane] = c0;
            lO[((ic + 4) * 4 + w4) * 64 + lane] = c1;
        }
        if (hi == 0) lL[w4 * 32 + l32] = l_pair;
    }
    __syncthreads();
    if (grp == 0) {
#pragma unroll
        for (int ic = 0; ic < 4; ++ic) {
            const fx4 c0 = lO[(ic * 4 + w4) * 64 + lane];
            const fx4 c1 = lO[((ic + 4) * 4 + w4) * 64 + lane];
#pragma unroll
            for (int r = 0; r < 4; ++r) { ov0[ic * 4 + r] += c0[r]; ov1[ic * 4 + r] += c1[r]; }
        }
        const float inv_l = 1.0f / (l_pair + lL[w4 * 32 + l32]);
#pragma unroll
        for (int dt = 0; dt < 2; ++dt)
#pragma unroll
            for (int rg2 = 0; rg2 < 4; ++rg2) {
                bf16x4 o4;
#pragma unroll
                for (int r = 0; r < 4; ++r)
                    o4[r] = (__bf16)((dt ? ov1[rg2 * 4 + r] : ov0[rg2 * 4 + r]) * inv_l);
                const int col = h * 64 + dt * 32 + rg2 * 8 + hi * 4;
                *(bf16x4*)(O + (size_t)qrow * 2048 + col) = o4;
            }
    }
}

// ----------------------------------------------------------------------------
extern "C" void kernel_launch(void* const* d_in, const int* in_sizes, int n_in,
                              void* d_out, int out_size, void* d_ws, size_t ws_size,
                              hipStream_t stream) {
    const float* x  = (const float*)d_in[0];
    const float* wq = (const float*)d_in[1];
    const float* wk = (const float*)d_in[2];
    const float* wv = (const float*)d_in[3];
    const float* wo = (const float*)d_in[4];
    float* out = (float*)d_out;
    char* ws = (char*)d_ws;

    __bf16* Xb    = (__bf16*)ws;                        // [0, 8M)
    __bf16* WqkvT = (__bf16*)(ws + ((size_t)8 << 20));  // [8M, 20M)  3072 x 2048
    __bf16* WoT   = (__bf16*)(ws + ((size_t)20 << 20)); // [20M, 28M) 2048 x 2048
    __bf16* Qr    = (__bf16*)(ws + ((size_t)28 << 20)); // [28M, 36M) 32 x 2048 x 64
    __bf16* Kr    = (__bf16*)(ws + ((size_t)36 << 20)); // [36M, 38M)  8 x 2048 x 64
    __bf16* Vt    = (__bf16*)(ws + ((size_t)38 << 20)); // [38M, 40M)  8 x 64 x 2048
    __bf16* Ob    = (__bf16*)(ws + ((size_t)40 << 20)); // [40M, 48M) 2048 x 2048

    prep<<<4096 + 5120, 256, 0, stream>>>((const float4*)x, Xb, wq, wk, wv, wo, WqkvT, WoT);
    gemm_qkv<<<dim3(16, 48), 256, 0, stream>>>(Xb, WqkvT, Qr, Kr, Vt);
    flash_attn<<<dim3(16, 32), 512, 0, stream>>>(Qr, Kr, Vt, Ob);
    gemm_out<<<dim3(16, 32), 256, 0, stream>>>(Ob, WoT, out);
}

// Round 3
// 199.836 us; speedup vs baseline: 1.0778x; 1.0778x over previous
//
#include <hip/hip_runtime.h>
#include <hip/hip_bf16.h>

typedef __bf16 bf16x8 __attribute__((ext_vector_type(8)));
typedef __bf16 bf16x4 __attribute__((ext_vector_type(4)));
typedef __bf16 bf16x2 __attribute__((ext_vector_type(2)));
typedef float fx4 __attribute__((ext_vector_type(4)));
typedef float fx16 __attribute__((ext_vector_type(16)));

#define AS1 __attribute__((address_space(1)))
#define AS3 __attribute__((address_space(3)))

// ---------------------------------------------------------------- prep: cast x -> bf16  +  all 4 weight transposes
__global__ __launch_bounds__(256) void prep(const float4* __restrict__ X, __bf16* __restrict__ Xb,
                                            const float* __restrict__ wq, const float* __restrict__ wk,
                                            const float* __restrict__ wv, const float* __restrict__ wo,
                                            __bf16* __restrict__ WqkvT, __bf16* __restrict__ WoT) {
    const int bx = blockIdx.x;
    if (bx < 4096) {
        const int i = bx * 256 + threadIdx.x;
        const float4 v = X[i];
        bf16x4 o = { (__bf16)v.x, (__bf16)v.y, (__bf16)v.z, (__bf16)v.w };
        *(bf16x4*)(Xb + (size_t)i * 4) = o;
        return;
    }
    constexpr int K = 2048;
    __shared__ float t[64][33];
    const int tt = bx - 4096;
    const float* W; __bf16* Wt; int N, loc;
    if (tt < 2048)      { W = wq; Wt = WqkvT;                       N = 2048; loc = tt; }
    else if (tt < 2560) { W = wk; Wt = WqkvT + (size_t)2048 * 2048; N = 512;  loc = tt - 2048; }
    else if (tt < 3072) { W = wv; Wt = WqkvT + (size_t)2560 * 2048; N = 512;  loc = tt - 2560; }
    else                { W = wo; Wt = WoT;                         N = 2048; loc = tt - 3072; }
    const int k0 = (loc & 31) * 64, n0 = (loc >> 5) * 32;
    const int tx = threadIdx.x & 31, ty = threadIdx.x >> 5;
#pragma unroll
    for (int i = 0; i < 8; ++i)
        t[ty + i * 8][tx] = W[(size_t)(k0 + ty + i * 8) * N + n0 + tx];
    __syncthreads();
#pragma unroll
    for (int i = 0; i < 4; ++i) {
        const int nn = ty + i * 8;
        bf16x2 o = { (__bf16)t[tx * 2][nn], (__bf16)t[tx * 2 + 1][nn] };
        *(bf16x2*)&Wt[(size_t)(n0 + nn) * K + k0 + tx * 2] = o;
    }
}

// ================================================= shared GEMM body: BM=128 BN=128 BK=32,
// 4 waves (64x64 wave-tile), 4-buffer depth-3 counted-vmcnt ring, static buffer indices,
// XOR-swizzled LDS.  acc[4][4], af[4]/bfr[4] per K-step: 16 MFMA : 8 ds_read_b128.
#define GEMM_SETUP(Aptr, Btptr)                                                              \
    constexpr int K = 2048;                                                                  \
    __shared__ __align__(16) __bf16 sm[4][8192];    /* 64 KB */                              \
    const int tid = threadIdx.x;                                                             \
    const int wave = tid >> 6, lane = tid & 63;                                              \
    const int quad = lane >> 4, l16 = lane & 15;                                             \
    const int wm = (wave >> 1) * 64, wn = (wave & 1) * 64;                                   \
    fx4 acc[4][4] = {};                                                                      \
    const int r4 = lane >> 2;                                                                \
    const int c8s = ((lane & 3) ^ ((r4 >> 1) & 3)) * 8;                                      \
    const __bf16* csrc[4]; int cdst[4];                                                      \
    _Pragma("unroll")                                                                        \
    for (int it = 0; it < 4; ++it) {                                                         \
        const int idx = wave * 4 + it;                                                       \
        if (idx < 8) { csrc[it] = (Aptr) + (size_t)(m0 + idx * 16 + r4) * K + c8s;           \
                       cdst[it] = idx * 512 + lane * 8; }                                    \
        else         { csrc[it] = (Btptr) + (size_t)(n0 + (idx - 8) * 16 + r4) * K + c8s;    \
                       cdst[it] = 4096 + (idx - 8) * 512 + lane * 8; }                       \
    }                                                                                        \
    const int colr = (quad ^ ((l16 >> 1) & 3)) * 8;                                          \
    const int arow = (wm + l16) * 32 + colr;                                                 \
    const int brow = 4096 + (wn + l16) * 32 + colr;                                          \
    auto compute = [&](const __bf16* cb) {                                                   \
        bf16x8 af[4], bfr[4];                                                                \
        _Pragma("unroll") for (int i = 0; i < 4; ++i) af[i]  = *(const bf16x8*)&cb[arow + i * 512]; \
        _Pragma("unroll") for (int j = 0; j < 4; ++j) bfr[j] = *(const bf16x8*)&cb[brow + j * 512]; \
        __builtin_amdgcn_s_setprio(1);                                                       \
        _Pragma("unroll") for (int i = 0; i < 4; ++i)                                        \
            _Pragma("unroll") for (int j = 0; j < 4; ++j)                                    \
                acc[i][j] = __builtin_amdgcn_mfma_f32_16x16x32_bf16(af[i], bfr[j], acc[i][j], 0, 0, 0); \
        __builtin_amdgcn_s_setprio(0);                                                       \
    };                                                                                       \
    _Pragma("unroll")                                                                        \
    for (int pt = 0; pt < 3; ++pt)                                                           \
        _Pragma("unroll")                                                                    \
        for (int it = 0; it < 4; ++it)                                                       \
            __builtin_amdgcn_global_load_lds((const AS1 void*)(csrc[it] + pt * 32),          \
                                             (AS3 void*)&sm[pt][cdst[it]], 16, 0, 0);        \
    _Pragma("unroll 1")                                                                      \
    for (int tq = 0; tq < 15; ++tq) {                                                        \
        const int t0 = tq * 4;                                                               \
        _Pragma("unroll")                                                                    \
        for (int u = 0; u < 4; ++u) {                                                        \
            asm volatile("s_waitcnt vmcnt(8) lgkmcnt(0)" ::: "memory");                      \
            __builtin_amdgcn_s_barrier();                                                    \
            __builtin_amdgcn_sched_barrier(0);                                               \
            const int tile = t0 + u + 3;                                                     \
            const int kofs = tile * 32;                                                      \
            _Pragma("unroll")                                                                \
            for (int it = 0; it < 4; ++it)                                                   \
                __builtin_amdgcn_global_load_lds((const AS1 void*)(csrc[it] + kofs),         \
                                                 (AS3 void*)&sm[(u + 3) & 3][cdst[it]], 16, 0, 0); \
            compute(sm[u]);                                                                  \
        }                                                                                    \
    }                                                                                        \
    { /* t = 60: issue last tile (63) into buf 3, compute buf 0 */                           \
        asm volatile("s_waitcnt vmcnt(8) lgkmcnt(0)" ::: "memory");                          \
        __builtin_amdgcn_s_barrier();                                                        \
        __builtin_amdgcn_sched_barrier(0);                                                   \
        _Pragma("unroll")                                                                    \
        for (int it = 0; it < 4; ++it)                                                       \
            __builtin_amdgcn_global_load_lds((const AS1 void*)(csrc[it] + 63 * 32),          \
                                             (AS3 void*)&sm[3][cdst[it]], 16, 0, 0);         \
        compute(sm[0]);                                                                      \
    }                                                                                        \
    asm volatile("s_waitcnt vmcnt(8) lgkmcnt(0)" ::: "memory"); __builtin_amdgcn_s_barrier();\
    __builtin_amdgcn_sched_barrier(0); compute(sm[1]);                                       \
    asm volatile("s_waitcnt vmcnt(4) lgkmcnt(0)" ::: "memory"); __builtin_amdgcn_s_barrier();\
    __builtin_amdgcn_sched_barrier(0); compute(sm[2]);                                       \
    asm volatile("s_waitcnt vmcnt(0) lgkmcnt(0)" ::: "memory"); __builtin_amdgcn_s_barrier();\
    __builtin_amdgcn_sched_barrier(0); compute(sm[3]);

// ------------------------------------------------- QKV GEMM with fused RoPE/split epilogue
__global__ __launch_bounds__(256, 2) void gemm_qkv(const __bf16* __restrict__ A, const __bf16* __restrict__ Bt,
                                                   __bf16* __restrict__ Qr, __bf16* __restrict__ Kr,
                                                   __bf16* __restrict__ Vt) {
    // XCD-chunked swizzle, nwg = 384 = 8*48
    const int bid = blockIdx.x;
    const int swz = (bid & 7) * 48 + (bid >> 3);
    const int m0 = (swz & 15) * 128, n0 = (swz >> 4) * 128;

    GEMM_SETUP(A, Bt)

    // epilogue: each wave's 64 cols (col64..col64+63) are exactly one head
    const int col64 = n0 + wn;
    if (col64 < 2560) {
        // Q (col64 < 2048) or K: RoPE rotate-half, d pairs (dlo, dlo+32)
        const bool isQ = col64 < 2048;
        const float scale = isQ ? 0.18033688011112042f : 1.0f;   // Q: 0.125*log2(e)
        __bf16* base = isQ ? (Qr + (size_t)(col64 >> 6) * 2048 * 64)
                           : (Kr + (size_t)((col64 - 2048) >> 6) * 2048 * 64);
#pragma unroll
        for (int jj = 0; jj < 2; ++jj) {
            const int dlo = jj * 16 + l16;
            const float inv = __builtin_amdgcn_exp2f(-(float)dlo * 0.41524101186092029f);
#pragma unroll
            for (int i = 0; i < 4; ++i)
#pragma unroll
                for (int r = 0; r < 4; ++r) {
                    const int s = m0 + wm + i * 16 + quad * 4 + r;
                    float sn, cs;
                    __sincosf((float)s * inv, &sn, &cs);
                    const float lo = acc[i][jj][r], hv = acc[i][jj + 2][r];
                    base[(size_t)s * 64 + dlo]      = (__bf16)((lo * cs - hv * sn) * scale);
                    base[(size_t)s * 64 + dlo + 32] = (__bf16)((hv * cs + lo * sn) * scale);
                }
        }
    } else {
        __bf16* vb = Vt + (size_t)((col64 - 2560) >> 6) * 64 * 2048;
#pragma unroll
        for (int i = 0; i < 4; ++i)
#pragma unroll
            for (int j = 0; j < 4; ++j) {
                const int d = j * 16 + l16;
                const int s0 = m0 + wm + i * 16 + quad * 4;
                bf16x4 p;
#pragma unroll
                for (int r = 0; r < 4; ++r) p[r] = (__bf16)acc[i][j][r];
                *(bf16x4*)&vb[(size_t)d * 2048 + s0] = p;
            }
    }
}

// ------------------------------------------------- out-projection GEMM, f32 C direct
__global__ __launch_bounds__(256, 2) void gemm_out(const __bf16* __restrict__ A, const __bf16* __restrict__ Bt,
                                                   float* __restrict__ C) {
    // XCD-chunked swizzle, nwg = 256 = 8*32
    const int bid = blockIdx.x;
    const int swz = (bid & 7) * 32 + (bid >> 3);
    const int m0 = (swz & 15) * 128, n0 = (swz >> 4) * 128;

    GEMM_SETUP(A, Bt)

#pragma unroll
    for (int i = 0; i < 4; ++i)
#pragma unroll
        for (int j = 0; j < 4; ++j) {
            const int row = m0 + wm + i * 16 + quad * 4;
            const int col = n0 + wn + j * 16 + l16;
#pragma unroll
            for (int r = 0; r < 4; ++r)
                C[(size_t)(row + r) * 2048 + col] = acc[i][j][r];
        }
}

// ------------------------------------------------- flash attention: no-P-LDS + 8-wave split-K + LDS dbuf
// In-loop barriers are raw s_barrier + lgkmcnt(0) ONLY — K/V register prefetch loads ride
// across the barrier (vmcnt waited at their register use, under ~500cyc of compute slack).
__global__ __launch_bounds__(512, 4) void flash_attn(const __bf16* __restrict__ Qr, const __bf16* __restrict__ Kr,
                                                     const __bf16* __restrict__ Vt, __bf16* __restrict__ O) {
    constexpr int S = 2048;
    __shared__ __align__(16) __bf16 smem[2][4 * 64 * 72];   // 73728 B, 2 buffers
    const int qt = blockIdx.x, h = blockIdx.y, kvh = h >> 2;
    const int tid = threadIdx.x, wave = tid >> 6, lane = tid & 63;
    const int grp = wave >> 2, w4 = wave & 3;
    const int l32 = lane & 31, hi = lane >> 5;
    const int goff = grp * 2 * 4608;                        // group's K/V region inside a buffer

    const int qrow = qt * 128 + w4 * 32 + l32;
    const __bf16* qptr = Qr + ((size_t)h * S + qrow) * 64;
    bf16x8 qf[4];
#pragma unroll
    for (int kc = 0; kc < 4; ++kc) qf[kc] = *(const bf16x8*)(qptr + kc * 16 + hi * 8);

    const __bf16* Kbase = Kr + (size_t)kvh * S * 64;
    const __bf16* Vbase = Vt + (size_t)kvh * 64 * S;

    const int gtid = tid & 255;
    const int krow = gtid >> 3;                 // 0..31
    const int kcol = (gtid & 7) * 8;
    const int vslot = (kcol & 48) | ((kcol & 8) >> 1);   // permuted dest of keys [kcol, kcol+4)

    // prefetch tile 0 of this group (kt = grp)
    bf16x8 kreg0 = *(const bf16x8*)(Kbase + (size_t)(grp * 64 + krow) * 64 + kcol);
    bf16x8 kreg1 = *(const bf16x8*)(Kbase + (size_t)(grp * 64 + 32 + krow) * 64 + kcol);
    bf16x8 vreg0 = *(const bf16x8*)(Vbase + (size_t)krow * S + grp * 64 + kcol);
    bf16x8 vreg1 = *(const bf16x8*)(Vbase + (size_t)(32 + krow) * S + grp * 64 + kcol);

    fx16 ov0, ov1;
#pragma unroll
    for (int i = 0; i < 16; ++i) { ov0[i] = 0.f; ov1[i] = 0.f; }
    float l_acc = 0.f;

    // stage tile 0 into buf 0, then prefetch tile 1 (kt = 2 + grp)
    {
        __bf16* nK = &smem[0][goff];
        __bf16* nV = nK + 4608;
        *(bf16x8*)&nK[krow * 72 + kcol] = kreg0;
        *(bf16x8*)&nK[(32 + krow) * 72 + kcol] = kreg1;
        bf16x4 v0lo = { vreg0[0], vreg0[1], vreg0[2], vreg0[3] };
        bf16x4 v0hi = { vreg0[4], vreg0[5], vreg0[6], vreg0[7] };
        bf16x4 v1lo = { vreg1[0], vreg1[1], vreg1[2], vreg1[3] };
        bf16x4 v1hi = { vreg1[4], vreg1[5], vreg1[6], vreg1[7] };
        *(bf16x4*)&nV[krow * 72 + vslot]            = v0lo;
        *(bf16x4*)&nV[krow * 72 + vslot + 8]        = v0hi;
        *(bf16x4*)&nV[(32 + krow) * 72 + vslot]     = v1lo;
        *(bf16x4*)&nV[(32 + krow) * 72 + vslot + 8] = v1hi;
        const int kt1 = 2 + grp;
        kreg0 = *(const bf16x8*)(Kbase + (size_t)(kt1 * 64 + krow) * 64 + kcol);
        kreg1 = *(const bf16x8*)(Kbase + (size_t)(kt1 * 64 + 32 + krow) * 64 + kcol);
        vreg0 = *(const bf16x8*)(Vbase + (size_t)krow * S + kt1 * 64 + kcol);
        vreg1 = *(const bf16x8*)(Vbase + (size_t)(32 + krow) * S + kt1 * 64 + kcol);
    }
    asm volatile("s_waitcnt lgkmcnt(0)" ::: "memory");
    __builtin_amdgcn_s_barrier();
    __builtin_amdgcn_sched_barrier(0);

    for (int it = 0; it < 16; ++it) {
        __bf16* lKg = &smem[it & 1][goff];
        __bf16* lVg = lKg + 4608;

        // stage tile it+1 into the other buffer; prefetch tile it+2
        if (it + 1 < 16) {
            __bf16* nK = &smem[(it + 1) & 1][goff];
            __bf16* nV = nK + 4608;
            *(bf16x8*)&nK[krow * 72 + kcol] = kreg0;
            *(bf16x8*)&nK[(32 + krow) * 72 + kcol] = kreg1;
            bf16x4 v0lo = { vreg0[0], vreg0[1], vreg0[2], vreg0[3] };
            bf16x4 v0hi = { vreg0[4], vreg0[5], vreg0[6], vreg0[7] };
            bf16x4 v1lo = { vreg1[0], vreg1[1], vreg1[2], vreg1[3] };
            bf16x4 v1hi = { vreg1[4], vreg1[5], vreg1[6], vreg1[7] };
            *(bf16x4*)&nV[krow * 72 + vslot]            = v0lo;
            *(bf16x4*)&nV[krow * 72 + vslot + 8]        = v0hi;
            *(bf16x4*)&nV[(32 + krow) * 72 + vslot]     = v1lo;
            *(bf16x4*)&nV[(32 + krow) * 72 + vslot + 8] = v1hi;
            const int it2 = (it + 2 < 16) ? it + 2 : 15;   // clamped (redundant reload ok)
            const int ktn = it2 * 2 + grp;
            kreg0 = *(const bf16x8*)(Kbase + (size_t)(ktn * 64 + krow) * 64 + kcol);
            kreg1 = *(const bf16x8*)(Kbase + (size_t)(ktn * 64 + 32 + krow) * 64 + kcol);
            vreg0 = *(const bf16x8*)(Vbase + (size_t)krow * S + ktn * 64 + kcol);
            vreg1 = *(const bf16x8*)(Vbase + (size_t)(32 + krow) * S + ktn * 64 + kcol);
        }

        // S^T = K . Q^T  (k-chunks of 16 d)
        fx16 sc0, sc1;
#pragma unroll
        for (int i = 0; i < 16; ++i) { sc0[i] = 0.f; sc1[i] = 0.f; }
        __builtin_amdgcn_s_setprio(1);
#pragma unroll
        for (int kc = 0; kc < 4; ++kc) {
            const bf16x8 a0 = *(const bf16x8*)&lKg[l32 * 72 + kc * 16 + hi * 8];
            const bf16x8 a1 = *(const bf16x8*)&lKg[(32 + l32) * 72 + kc * 16 + hi * 8];
            sc0 = __builtin_amdgcn_mfma_f32_32x32x16_bf16(a0, qf[kc], sc0, 0, 0, 0);
            sc1 = __builtin_amdgcn_mfma_f32_32x32x16_bf16(a1, qf[kc], sc1, 0, 0, 0);
        }
        __builtin_amdgcn_s_setprio(0);

        // fixed-max softmax (p = exp2(s), Q pre-scaled) fused straight into PV
#pragma unroll
        for (int h2 = 0; h2 < 2; ++h2) {
#pragma unroll
            for (int c = 0; c < 2; ++c) {
                bf16x8 pb;
#pragma unroll
                for (int j = 0; j < 8; ++j) {
                    const float sv = h2 ? sc1[c * 8 + j] : sc0[c * 8 + j];
                    const float p = __builtin_amdgcn_exp2f(sv);
                    l_acc += p;
                    pb[j] = (__bf16)p;
                }
                const int kcv = h2 * 2 + c;
                const bf16x8 va0 = *(const bf16x8*)&lVg[l32 * 72 + kcv * 16 + hi * 8];
                const bf16x8 va1 = *(const bf16x8*)&lVg[(32 + l32) * 72 + kcv * 16 + hi * 8];
                __builtin_amdgcn_s_setprio(1);
                ov0 = __builtin_amdgcn_mfma_f32_32x32x16_bf16(va0, pb, ov0, 0, 0, 0);
                ov1 = __builtin_amdgcn_mfma_f32_32x32x16_bf16(va1, pb, ov1, 0, 0, 0);
                __builtin_amdgcn_s_setprio(0);
            }
        }
        asm volatile("s_waitcnt lgkmcnt(0)" ::: "memory");
        __builtin_amdgcn_s_barrier();
        __builtin_amdgcn_sched_barrier(0);
    }

    // per-wave l over this group's keys (partner lane^32 holds complement)
    const float l_pair = l_acc + __shfl_xor(l_acc, 32, 64);

    // cross-group combine, overlaid on smem[0]
    fx4* lO = (fx4*)&smem[0][0];                 // [8 chunks][4 w4][64 lanes]
    float* lL = (float*)(&smem[0][0] + 16384);   // byte 32768
    if (grp == 1) {
#pragma unroll
        for (int ic = 0; ic < 4; ++ic) {
            fx4 c0, c1;
#pragma unroll
            for (int r = 0; r < 4; ++r) { c0[r] = ov0[ic * 4 + r]; c1[r] = ov1[ic * 4 + r]; }
            lO[(ic * 4 + w4) * 64 + lane] = c0;
            lO[((ic + 4) * 4 + w4) * 64 + lane] = c1;
        }
        if (hi == 0) lL[w4 * 32 + l32] = l_pair;
    }
    __syncthreads();
    if (grp == 0) {
#pragma unroll
        for (int ic = 0; ic < 4; ++ic) {
            const fx4 c0 = lO[(ic * 4 + w4) * 64 + lane];
            const fx4 c1 = lO[((ic + 4) * 4 + w4) * 64 + lane];
#pragma unroll
            for (int r = 0; r < 4; ++r) { ov0[ic * 4 + r] += c0[r]; ov1[ic * 4 + r] += c1[r]; }
        }
        const float inv_l = 1.0f / (l_pair + lL[w4 * 32 + l32]);
#pragma unroll
        for (int dt = 0; dt < 2; ++dt)
#pragma unroll
            for (int rg2 = 0; rg2 < 4; ++rg2) {
                bf16x4 o4;
#pragma unroll
                for (int r = 0; r < 4; ++r)
                    o4[r] = (__bf16)((dt ? ov1[rg2 * 4 + r] : ov0[rg2 * 4 + r]) * inv_l);
                const int col = h * 64 + dt * 32 + rg2 * 8 + hi * 4;
                *(bf16x4*)(O + (size_t)qrow * 2048 + col) = o4;
            }
    }
}

// ----------------------------------------------------------------------------
extern "C" void kernel_launch(void* const* d_in, const int* in_sizes, int n_in,
                              void* d_out, int out_size, void* d_ws, size_t ws_size,
                              hipStream_t stream) {
    const float* x  = (const float*)d_in[0];
    const float* wq = (const float*)d_in[1];
    const float* wk = (const float*)d_in[2];
    const float* wv = (const float*)d_in[3];
    const float* wo = (const float*)d_in[4];
    float* out = (float*)d_out;
    char* ws = (char*)d_ws;

    __bf16* Xb    = (__bf16*)ws;                        // [0, 8M)
    __bf16* WqkvT = (__bf16*)(ws + ((size_t)8 << 20));  // [8M, 20M)  3072 x 2048
    __bf16* WoT   = (__bf16*)(ws + ((size_t)20 << 20)); // [20M, 28M) 2048 x 2048
    __bf16* Qr    = (__bf16*)(ws + ((size_t)28 << 20)); // [28M, 36M) 32 x 2048 x 64
    __bf16* Kr    = (__bf16*)(ws + ((size_t)36 << 20)); // [36M, 38M)  8 x 2048 x 64
    __bf16* Vt    = (__bf16*)(ws + ((size_t)38 << 20)); // [38M, 40M)  8 x 64 x 2048
    __bf16* Ob    = (__bf16*)(ws + ((size_t)40 << 20)); // [40M, 48M) 2048 x 2048

    prep<<<4096 + 5120, 256, 0, stream>>>((const float4*)x, Xb, wq, wk, wv, wo, WqkvT, WoT);
    gemm_qkv<<<384, 256, 0, stream>>>(Xb, WqkvT, Qr, Kr, Vt);
    flash_attn<<<dim3(16, 32), 512, 0, stream>>>(Qr, Kr, Vt, Ob);
    gemm_out<<<256, 256, 0, stream>>>(Ob, WoT, out);
}